// Round 2
// baseline (1282.303 us; speedup 1.0000x reference)
//
#include <hip/hip_runtime.h>
#include <hip/hip_bf16.h>

typedef unsigned short u16;
typedef unsigned int   u32;
typedef short bf16x8 __attribute__((ext_vector_type(8)));   // 8 bf16 = 4 VGPRs (MFMA A/B frag)
typedef float f32x4  __attribute__((ext_vector_type(4)));   // MFMA C/D frag

#define N_PTS   524288

// ws layout (u16 element offsets). Grids stored channel-last bf16 (voxel-major, 16ch).
#define WS_TAU   18939904
#define WS_MAP   37879808
#define WS_TMLP  37912576
#define WS_MLP   37928960
#define WS_TOTAL_BYTES (37978112ULL * 2ULL)

// Compiler memory fence: keeps differently-typed LDS reads/writes of the act
// tile from being reordered (TBAA insurance; zero runtime cost).
__device__ __forceinline__ void ldsfence() { __asm__ __volatile__("" ::: "memory"); }

// ---------- bf16 / fast-math helpers ----------
// NOTE: reverted to the round-0-verified f2b packing (no inline-asm cvt_pk):
// the v_cvt_pk_bf16_f32 asm was the only unverifiable-new primitive in the
// NaN'd round-1 kernel, and it touched every datapath. Bisection first.
__device__ __forceinline__ float b2f(u16 b) {
    u32 u = ((u32)b) << 16; float f; __builtin_memcpy(&f, &u, 4); return f;
}
__device__ __forceinline__ u16 f2b(float f) {
    u32 u; __builtin_memcpy(&u, &f, 4);
    u32 r = (u + 0x7FFFu + ((u >> 16) & 1u)) >> 16;   // RNE
    return (u16)r;
}
// v_rcp_f32: ~1ulp approx — fine at our 2% tolerance, replaces ~10-inst IEEE div
__device__ __forceinline__ float frcp(float x) { return __builtin_amdgcn_rcpf(x); }
__device__ __forceinline__ float fsilu(float x) { return x * frcp(1.f + __expf(-x)); }
__device__ __forceinline__ float ftanh(float x) {
    float e = __expf(2.f * x);
    return 1.f - 2.f * frcp(e + 1.f);
}
// v_sin_f32 takes revolutions; |arg| <= ~7 rad = 1.2 rev here (well in range)
__device__ __forceinline__ float fsin(float a) {
    return __builtin_amdgcn_sinf(a * 0.15915494309189535f);
}

// act LDS index, XOR swizzle on 16B chunks (breaks 256B power-of-2 row stride).
// Any access within one 8-elem chunk (4- or 8-aligned groups) stays contiguous.
__device__ __forceinline__ int aidx(int row, int ch) {
    return (row << 7) + ((((ch >> 3) ^ (row & 7))) << 3) + (ch & 7);
}

__device__ __forceinline__ void store4(u16* actw, int row, int ch,
                                       float v0, float v1, float v2, float v3) {
    u32 lo = (u32)f2b(v0) | ((u32)f2b(v1) << 16);
    u32 hi = (u32)f2b(v2) | ((u32)f2b(v3) << 16);
    *(uint2*)(actw + aidx(row, ch)) = make_uint2(lo, hi);   // ds_write_b64
}

struct GridPtrs { const float* g[4]; };

// ---------- fused prep: 8 grid transposes (f32 C-major -> bf16 channel-last) + 3 weight cvts ----------
struct PrepArgs {
    const float* vg[4]; const float* tg[4];
    const float* map_w; const float* tmlp; const float* mlp;
    u16* ws;
};
#define PREP_VOXB 9248   // 2*1183744 / 256
__global__ void __launch_bounds__(256) dtn_prep(PrepArgs p) {
    int b = blockIdx.x;
    if (b < PREP_VOXB) {
        int v = b * 256 + threadIdx.x;          // global voxel id over both grid sets
        int set = (v >= 1183744) ? 1 : 0;
        int lv = v - set * 1183744;
        int l, base, S3, off;
        if      (lv <   4096) { l = 0; base = 0;      S3 = 4096;   off = 0;       }
        else if (lv <  36864) { l = 1; base = 4096;   S3 = 32768;  off = 65536;   }
        else if (lv < 299008) { l = 2; base = 36864;  S3 = 262144; off = 589824;  }
        else                  { l = 3; base = 299008; S3 = 884736; off = 4784128; }
        int vox = lv - base;
        const float* src = set ? p.tg[l] : p.vg[l];
        u16* dst = p.ws + (set ? WS_TAU : 0) + off + (size_t)vox * 16;
        u32 packed[8];
#pragma unroll
        for (int c = 0; c < 8; ++c) {
            u32 lo = f2b(src[(2 * c) * S3 + vox]);
            u32 hi = f2b(src[(2 * c + 1) * S3 + vox]);
            packed[c] = lo | (hi << 16);
        }
        uint4* d = (uint4*)dst;
        d[0] = make_uint4(packed[0], packed[1], packed[2], packed[3]);
        d[1] = make_uint4(packed[4], packed[5], packed[6], packed[7]);
    } else {
        int i = (b - PREP_VOXB) * 256 + threadIdx.x;   // weights: 98304 elems total
        if (i < 32768)      p.ws[WS_MAP  + i]          = f2b(p.map_w[i]);
        else if (i < 49152) p.ws[WS_TMLP + (i - 32768)] = f2b(p.tmlp[i - 32768]);
        else if (i < 98304) p.ws[WS_MLP  + (i - 49152)] = f2b(p.mlp[i - 49152]);
    }
}

// ---------- featurize, 4-way split: wave w = grid level w (16ch) + FFM chans [w*16, w*16+16) ----------
template<int USE_WS, int LVL>
__device__ __forceinline__ void fz_level(const u16* __restrict__ gT,
                                         const float* __restrict__ gf,
                                         float x, float y, float z,
                                         u16* __restrict__ actw, int row)
{
    constexpr int S   = (LVL == 0) ? 16 : (LVL == 1) ? 32 : (LVL == 2) ? 64 : 96;
    constexpr int OFF = (LVL == 0) ? 0 : (LVL == 1) ? 65536 : (LVL == 2) ? 589824 : 4784128;
    constexpr int S3  = S * S * S;
    const float fS = (float)(S - 1);
    float px = fminf(fmaxf((x + 1.f) * 0.5f * fS, 0.f), fS);
    float py = fminf(fmaxf((y + 1.f) * 0.5f * fS, 0.f), fS);
    float pz = fminf(fmaxf((z + 1.f) * 0.5f * fS, 0.f), fS);
    int ix0 = (int)px, iy0 = (int)py, iz0 = (int)pz;
    float wx = px - (float)ix0, wy = py - (float)iy0, wz = pz - (float)iz0;
    int ix1 = min(ix0 + 1, S - 1), iy1 = min(iy0 + 1, S - 1), iz1 = min(iz0 + 1, S - 1);

    float f[16];
#pragma unroll
    for (int c = 0; c < 16; ++c) f[c] = 0.f;

#pragma unroll
    for (int cz = 0; cz < 2; ++cz) {
        int zz = cz ? iz1 : iz0;
        float wgtz = cz ? wz : (1.f - wz);
#pragma unroll
        for (int cy = 0; cy < 2; ++cy) {
            int yy = cy ? iy1 : iy0;
            float wgty = wgtz * (cy ? wy : (1.f - wy));
#pragma unroll
            for (int cx = 0; cx < 2; ++cx) {
                int xx = cx ? ix1 : ix0;
                float wgt = wgty * (cx ? wx : (1.f - wx));
                if (USE_WS) {
                    const uint4* p = (const uint4*)(gT + OFF + (size_t)(((zz * S) + yy) * S + xx) * 16);
                    uint4 a = p[0], b = p[1];
                    f[0]  += wgt * b2f((u16)(a.x & 0xffff));  f[1]  += wgt * b2f((u16)(a.x >> 16));
                    f[2]  += wgt * b2f((u16)(a.y & 0xffff));  f[3]  += wgt * b2f((u16)(a.y >> 16));
                    f[4]  += wgt * b2f((u16)(a.z & 0xffff));  f[5]  += wgt * b2f((u16)(a.z >> 16));
                    f[6]  += wgt * b2f((u16)(a.w & 0xffff));  f[7]  += wgt * b2f((u16)(a.w >> 16));
                    f[8]  += wgt * b2f((u16)(b.x & 0xffff));  f[9]  += wgt * b2f((u16)(b.x >> 16));
                    f[10] += wgt * b2f((u16)(b.y & 0xffff));  f[11] += wgt * b2f((u16)(b.y >> 16));
                    f[12] += wgt * b2f((u16)(b.z & 0xffff));  f[13] += wgt * b2f((u16)(b.z >> 16));
                    f[14] += wgt * b2f((u16)(b.w & 0xffff));  f[15] += wgt * b2f((u16)(b.w >> 16));
                } else {
                    size_t vox = (size_t)((zz * S) + yy) * S + xx;
#pragma unroll
                    for (int c = 0; c < 16; ++c)
                        f[c] += wgt * gf[(size_t)c * S3 + vox];
                }
            }
        }
    }
#pragma unroll
    for (int c = 0; c < 16; c += 4)
        store4(actw, row, LVL * 16 + c,
               fsilu(f[c]), fsilu(f[c + 1]), fsilu(f[c + 2]), fsilu(f[c + 3]));
}

template<int USE_WS, int HASB>
__device__ __forceinline__ void featurize4(const u16* __restrict__ gT, GridPtrs gp, int part,
                                           float x, float y, float z,
                                           const float* __restrict__ pe_w,
                                           const float* __restrict__ pe_b,
                                           u16* __restrict__ actw, int row)
{
    // part (= wave id) is wave-uniform: each wave takes exactly one branch.
    switch (part) {
        case 0:  fz_level<USE_WS, 0>(gT, gp.g[0], x, y, z, actw, row); break;
        case 1:  fz_level<USE_WS, 1>(gT, gp.g[1], x, y, z, actw, row); break;
        case 2:  fz_level<USE_WS, 2>(gT, gp.g[2], x, y, z, actw, row); break;
        default: fz_level<USE_WS, 3>(gT, gp.g[3], x, y, z, actw, row); break;
    }
    // FFM: sin(coords @ pe_w^T (+ b)) -> channels 64+part*16 .. 64+part*16+15
    const int f0 = part * 16;
#pragma unroll 4
    for (int fc = f0; fc < f0 + 16; fc += 4) {
        float s[4];
#pragma unroll
        for (int j = 0; j < 4; ++j) {
            int ch = fc + j;
            float a = x * pe_w[ch * 3 + 0] + y * pe_w[ch * 3 + 1] + z * pe_w[ch * 3 + 2];
            if (HASB) a += pe_b[ch];
            s[j] = fsin(a);
        }
        store4(actw, row, 64 + fc, s[0], s[1], s[2], s[3]);
    }
}

// ---------- per-wave 128x16 layer slice: wave w owns points w*16..w*16+15 (nt = w) ----------
__device__ __forceinline__ void loadB(const u16* actw, bf16x8 B[4], int row, int quad) {
#pragma unroll
    for (int kt = 0; kt < 4; ++kt)
        B[kt] = *(const bf16x8*)(actw + aidx(row, kt * 32 + quad * 8));
    ldsfence();   // pin loads BEFORE the in-place epilogue stores that follow
}

template<int USE_WS>
__device__ __forceinline__ bf16x8 loadA(const u16* WT, const float* Wf, int row, int chunk) {
    if (USE_WS) {
        return ((const bf16x8*)WT)[row * 16 + chunk];
    } else {
        const float4* p = (const float4*)(Wf + row * 128 + chunk * 8);
        float4 f0 = p[0], f1 = p[1];
        u32 w0 = (u32)f2b(f0.x) | ((u32)f2b(f0.y) << 16);
        u32 w1 = (u32)f2b(f0.z) | ((u32)f2b(f0.w) << 16);
        u32 w2 = (u32)f2b(f1.x) | ((u32)f2b(f1.y) << 16);
        u32 w3 = (u32)f2b(f1.z) | ((u32)f2b(f1.w) << 16);
        uint4 packed = make_uint4(w0, w1, w2, w3);
        bf16x8 r; __builtin_memcpy(&r, &packed, 16); return r;
    }
}

template<int USE_WS, typename Epi>
__device__ __forceinline__ void gemm128(const u16* __restrict__ WT, const float* __restrict__ Wf,
                                        const bf16x8 B[4],
                                        int l16, int quad, Epi&& epi)
{
#pragma unroll
    for (int mt = 0; mt < 8; ++mt) {
        f32x4 acc = (f32x4){0.f, 0.f, 0.f, 0.f};
#pragma unroll
        for (int kt = 0; kt < 4; ++kt) {
            // A frag: W[mt*16 + (lane&15)][kt*32 + quad*8 .. +7]
            bf16x8 a = loadA<USE_WS>(WT, Wf, mt * 16 + l16, kt * 4 + quad);
            acc = __builtin_amdgcn_mfma_f32_16x16x32_bf16(a, B[kt], acc, 0, 0, 0);
        }
        epi(mt, acc);
    }
}

// ---------- fused main kernel: one block = 4 waves = 64 points ----------
// 256-thread blocks over ONE 16 KiB act tile: 4 KiB LDS/wave; VGPR capped at 128
// by launch_bounds(256,4) -> 4 waves/SIMD (16 waves/CU) vs previous 2 (224 VGPR).
// Wave w: featurizes grid-level w for all 64 points, then owns output slice
// nt = w (points w*16..w*16+15) in every GEMM -> B[4] (16 regs) and tfpPk[16]
// instead of B[4][4]+tfpPk[64]. In GEMM phases each wave touches only its own
// 16 act rows, so layer-to-layer ordering is wave-local (barriers kept anyway).
template<int USE_WS>
__global__ void __launch_bounds__(256, 4)
dtn_main(const float* __restrict__ nc, const float* __restrict__ tauP,
         const float* __restrict__ phys, const u16* __restrict__ wsT,
         GridPtrs vgp, GridPtrs tgp,
         const float* __restrict__ vec_pe_w, const float* __restrict__ tau_pe_w,
         const float* __restrict__ tau_pe_b, const float* __restrict__ vscale,
         const float* __restrict__ map_w, const float* __restrict__ tau_mlp_w,
         const float* __restrict__ mlp_w, const float* __restrict__ tau_pars,
         const float* __restrict__ last_w, float* __restrict__ outP)
{
    __shared__ __align__(16) u16 actw[64 * 128];   // 16 KiB, one 64x128 bf16 tile
    const int tid  = threadIdx.x;
    const int w    = tid >> 6;            // wave id = featurize part = gemm nt
    const int lane = tid & 63;            // featurize row (point-in-block)
    const int quad = lane >> 4, l16 = lane & 15;
    const int row  = w * 16 + l16;        // gemm-phase act row (wave-private)

    const int pBase = blockIdx.x * 64;
    const int fzPt  = pBase + lane;       // point this thread featurizes
    const int myPt  = pBase + row;        // point this thread's gemm/head slice owns

    float cx = nc[fzPt * 3 + 0];
    float cy = nc[fzPt * 3 + 1];
    float cz = nc[fzPt * 3 + 2];
    float tauv = tauP[myPt];

    const u16* wsVec = wsT;
    const u16* wsTau = wsT + WS_TAU;
    const u16* wMap  = wsT + WS_MAP;
    const u16* wTmlp = wsT + WS_TMLP;
    const u16* wMlp  = wsT + WS_MLP;

    // ---- tau featurize (4-way level split across waves) ----
    featurize4<USE_WS, 1>(wsTau, tgp, w, cx, cy, cz, tau_pe_w, tau_pe_b, actw, lane);
    __syncthreads();

    // ---- tfp = tau_features @ tau_mlp_w^T  (packed bf16 in regs, C-frag layout) ----
    bf16x8 B[4];
    loadB(actw, B, row, quad);
    u32 tfpPk[16];
    gemm128<USE_WS>(wTmlp, tau_mlp_w, B, l16, quad, [&](int mt, f32x4 acc) {
        tfpPk[mt * 2 + 0] = (u32)f2b(acc[0]) | ((u32)f2b(acc[1]) << 16);
        tfpPk[mt * 2 + 1] = (u32)f2b(acc[2]) | ((u32)f2b(acc[3]) << 16);
    });
    __syncthreads();

    // ---- vec featurize (overwrite act) ----
    featurize4<USE_WS, 0>(wsVec, vgp, w, cx, cy, cz, vec_pe_w, (const float*)nullptr, actw, lane);
    __syncthreads();

    // ---- vec_map layer 0: act = silu(act @ W0^T) ----
    loadB(actw, B, row, quad);
    gemm128<USE_WS>(wMap, map_w, B, l16, quad, [&](int mt, f32x4 acc) {
        int cb = mt * 16 + quad * 4;
        store4(actw, row, cb, fsilu(acc[0]), fsilu(acc[1]), fsilu(acc[2]), fsilu(acc[3]));
    });
    __syncthreads();

    // ---- vec_map layer 1 fused with out-init: act = tanh(tau * vscale * silu(.)) ----
    loadB(actw, B, row, quad);
    gemm128<USE_WS>(wMap + 128 * 128, map_w + 128 * 128, B, l16, quad, [&](int mt, f32x4 acc) {
        int cb = mt * 16 + quad * 4;
        float4 vs = *(const float4*)(vscale + cb);
        store4(actw, row, cb,
               ftanh(tauv * vs.x * fsilu(acc[0])), ftanh(tauv * vs.y * fsilu(acc[1])),
               ftanh(tauv * vs.z * fsilu(acc[2])), ftanh(tauv * vs.w * fsilu(acc[3])));
    });
    __syncthreads();

    // ---- 3 residual layers: out += tanh(tau*tp) * silu(out @ Wv^T [* tfp @ idx0]) ----
#pragma unroll
    for (int idx = 0; idx < 3; ++idx) {
        loadB(actw, B, row, quad);
        gemm128<USE_WS>(wMlp + idx * 128 * 128, mlp_w + idx * 128 * 128, B, l16, quad,
                        [&](int mt, f32x4 acc) {
            int cb = mt * 16 + quad * 4;
            float4 tp = *(const float4*)(tau_pars + idx * 128 + cb);
            uint2 old = *(const uint2*)(actw + aidx(row, cb));
            float h0 = acc[0], h1 = acc[1], h2 = acc[2], h3 = acc[3];
            if (idx == 0) {
                h0 *= b2f((u16)(tfpPk[mt * 2] & 0xffff));
                h1 *= b2f((u16)(tfpPk[mt * 2] >> 16));
                h2 *= b2f((u16)(tfpPk[mt * 2 + 1] & 0xffff));
                h3 *= b2f((u16)(tfpPk[mt * 2 + 1] >> 16));
            }
            float n0 = b2f((u16)(old.x & 0xffff)) + ftanh(tauv * tp.x) * fsilu(h0);
            float n1 = b2f((u16)(old.x >> 16))    + ftanh(tauv * tp.y) * fsilu(h1);
            float n2 = b2f((u16)(old.y & 0xffff)) + ftanh(tauv * tp.z) * fsilu(h2);
            float n3 = b2f((u16)(old.y >> 16))    + ftanh(tauv * tp.w) * fsilu(h3);
            store4(actw, row, cb, n0, n1, n2, n3);
        });
        __syncthreads();
    }

    // ---- head: out = physical + act_row @ last_w^T  (3x128); lane does point `row`,
    //      k-segment quad*32..+31, then 2-step shfl_xor reduce across quads ----
    float a0 = 0.f, a1 = 0.f, a2 = 0.f;
#pragma unroll
    for (int c8 = 0; c8 < 4; ++c8) {
        int kb = quad * 32 + c8 * 8;
        bf16x8 v = *(const bf16x8*)(actw + aidx(row, kb));
        const u16* vp = (const u16*)&v;
#pragma unroll
        for (int j = 0; j < 8; ++j) {
            float av = b2f(vp[j]);
            int k = kb + j;
            a0 += av * last_w[0 * 128 + k];
            a1 += av * last_w[1 * 128 + k];
            a2 += av * last_w[2 * 128 + k];
        }
    }
    a0 += __shfl_xor(a0, 16); a0 += __shfl_xor(a0, 32);
    a1 += __shfl_xor(a1, 16); a1 += __shfl_xor(a1, 32);
    a2 += __shfl_xor(a2, 16); a2 += __shfl_xor(a2, 32);
    if (quad == 0) {
        outP[myPt * 3 + 0] = phys[myPt * 3 + 0] + a0;
        outP[myPt * 3 + 1] = phys[myPt * 3 + 1] + a1;
        outP[myPt * 3 + 2] = phys[myPt * 3 + 2] + a2;
    }
}

// ---------- launch ----------
extern "C" void kernel_launch(void* const* d_in, const int* in_sizes, int n_in,
                              void* d_out, int out_size, void* d_ws, size_t ws_size,
                              hipStream_t stream)
{
    // Supports both documented dict order (grids interleaved vec_g0,tau_g0,...)
    // and reference-signature order (vec_g0..3 then tau_g0..3). Slots 0-2 and
    // 11-19 are identical in both. Detect via in_sizes[4]: 65536 -> interleaved.
    const float* phys     = (const float*)d_in[0];
    const float* nc       = (const float*)d_in[1];
    const float* tau      = (const float*)d_in[2];
    GridPtrs vgp, tgp;
    bool interleaved = (in_sizes[4] == 65536);
    for (int l = 0; l < 4; ++l) {
        if (interleaved) {
            vgp.g[l] = (const float*)d_in[3 + 2 * l];
            tgp.g[l] = (const float*)d_in[4 + 2 * l];
        } else {
            vgp.g[l] = (const float*)d_in[3 + l];
            tgp.g[l] = (const float*)d_in[7 + l];
        }
    }
    const float* vec_pe_w = (const float*)d_in[11];
    const float* tau_pe_w = (const float*)d_in[12];
    const float* tau_pe_b = (const float*)d_in[13];
    const float* vscale   = (const float*)d_in[14];
    const float* map_w    = (const float*)d_in[15];
    const float* tau_mlp  = (const float*)d_in[16];
    const float* mlp_w    = (const float*)d_in[17];
    const float* tau_pars = (const float*)d_in[18];
    const float* last_w   = (const float*)d_in[19];
    u16* wsT = (u16*)d_ws;

    bool useWs = (ws_size >= WS_TOTAL_BYTES);
    if (useWs) {
        PrepArgs pa;
        for (int l = 0; l < 4; ++l) { pa.vg[l] = vgp.g[l]; pa.tg[l] = tgp.g[l]; }
        pa.map_w = map_w; pa.tmlp = tau_mlp; pa.mlp = mlp_w; pa.ws = wsT;
        dtn_prep<<<PREP_VOXB + 384, 256, 0, stream>>>(pa);
        dtn_main<1><<<N_PTS / 64, 256, 0, stream>>>(nc, tau, phys, wsT, vgp, tgp,
                                                    vec_pe_w, tau_pe_w, tau_pe_b, vscale,
                                                    map_w, tau_mlp, mlp_w, tau_pars, last_w,
                                                    (float*)d_out);
    } else {
        dtn_main<0><<<N_PTS / 64, 256, 0, stream>>>(nc, tau, phys, wsT, vgp, tgp,
                                                    vec_pe_w, tau_pe_w, tau_pe_b, vscale,
                                                    map_w, tau_mlp, mlp_w, tau_pars, last_w,
                                                    (float*)d_out);
    }
}

// Round 3
// 1131.417 us; speedup vs baseline: 1.1334x; 1.1334x over previous
//
#include <hip/hip_runtime.h>
#include <hip/hip_bf16.h>

typedef unsigned short u16;
typedef unsigned int   u32;
typedef short bf16x8 __attribute__((ext_vector_type(8)));   // 8 bf16 = 4 VGPRs (MFMA A/B frag)
typedef float f32x4  __attribute__((ext_vector_type(4)));   // MFMA C/D frag

#define N_PTS   524288

// ws layout (u16 element offsets). Grids stored channel-last bf16 (voxel-major, 16ch).
#define WS_TAU   18939904
#define WS_MAP   37879808
#define WS_TMLP  37912576
#define WS_MLP   37928960
#define WS_TOTAL_BYTES (37978112ULL * 2ULL)

// Compiler memory fence: keeps differently-typed LDS reads/writes of the act
// tile from being reordered (TBAA insurance; zero runtime cost).
__device__ __forceinline__ void ldsfence() { __asm__ __volatile__("" ::: "memory"); }

// ---------- bf16 / fast-math helpers ----------
__device__ __forceinline__ float b2f(u16 b) {
    u32 u = ((u32)b) << 16; float f; __builtin_memcpy(&f, &u, 4); return f;
}
__device__ __forceinline__ u16 f2b(float f) {
    u32 u; __builtin_memcpy(&u, &f, 4);
    u32 r = (u + 0x7FFFu + ((u >> 16) & 1u)) >> 16;   // RNE
    return (u16)r;
}
// v_rcp_f32: ~1ulp approx — fine at our 2% tolerance, replaces ~10-inst IEEE div
__device__ __forceinline__ float frcp(float x) { return __builtin_amdgcn_rcpf(x); }
__device__ __forceinline__ float fsilu(float x) { return x * frcp(1.f + __expf(-x)); }
__device__ __forceinline__ float ftanh(float x) {
    float e = __expf(2.f * x);
    return 1.f - 2.f * frcp(e + 1.f);
}
// v_sin_f32 takes revolutions; |arg| <= ~7 rad = 1.2 rev here (well in range)
__device__ __forceinline__ float fsin(float a) {
    return __builtin_amdgcn_sinf(a * 0.15915494309189535f);
}

// act LDS index, XOR swizzle on 16B chunks (breaks 256B power-of-2 row stride).
// Any access within one 8-elem chunk (4- or 8-aligned groups) stays contiguous.
__device__ __forceinline__ int aidx(int row, int ch) {
    return (row << 7) + ((((ch >> 3) ^ (row & 7))) << 3) + (ch & 7);
}

__device__ __forceinline__ void store4(u16* actw, int row, int ch,
                                       float v0, float v1, float v2, float v3) {
    u32 lo = (u32)f2b(v0) | ((u32)f2b(v1) << 16);
    u32 hi = (u32)f2b(v2) | ((u32)f2b(v3) << 16);
    *(uint2*)(actw + aidx(row, ch)) = make_uint2(lo, hi);   // ds_write_b64
}

struct GridPtrs { const float* g[4]; };

// ---------- fused prep: 8 grid transposes (f32 C-major -> bf16 channel-last) + 3 weight cvts ----------
struct PrepArgs {
    const float* vg[4]; const float* tg[4];
    const float* map_w; const float* tmlp; const float* mlp;
    u16* ws;
};
#define PREP_VOXB 9248   // 2*1183744 / 256
__global__ void __launch_bounds__(256) dtn_prep(PrepArgs p) {
    int b = blockIdx.x;
    if (b < PREP_VOXB) {
        int v = b * 256 + threadIdx.x;          // global voxel id over both grid sets
        int set = (v >= 1183744) ? 1 : 0;
        int lv = v - set * 1183744;
        int l, base, S3, off;
        if      (lv <   4096) { l = 0; base = 0;      S3 = 4096;   off = 0;       }
        else if (lv <  36864) { l = 1; base = 4096;   S3 = 32768;  off = 65536;   }
        else if (lv < 299008) { l = 2; base = 36864;  S3 = 262144; off = 589824;  }
        else                  { l = 3; base = 299008; S3 = 884736; off = 4784128; }
        int vox = lv - base;
        const float* src = set ? p.tg[l] : p.vg[l];
        u16* dst = p.ws + (set ? WS_TAU : 0) + off + (size_t)vox * 16;
        u32 packed[8];
#pragma unroll
        for (int c = 0; c < 8; ++c) {
            u32 lo = f2b(src[(2 * c) * S3 + vox]);
            u32 hi = f2b(src[(2 * c + 1) * S3 + vox]);
            packed[c] = lo | (hi << 16);
        }
        uint4* d = (uint4*)dst;
        d[0] = make_uint4(packed[0], packed[1], packed[2], packed[3]);
        d[1] = make_uint4(packed[4], packed[5], packed[6], packed[7]);
    } else {
        int i = (b - PREP_VOXB) * 256 + threadIdx.x;   // weights: 98304 elems total
        if (i < 32768)      p.ws[WS_MAP  + i]          = f2b(p.map_w[i]);
        else if (i < 49152) p.ws[WS_TMLP + (i - 32768)] = f2b(p.tmlp[i - 32768]);
        else if (i < 98304) p.ws[WS_MLP  + (i - 49152)] = f2b(p.mlp[i - 49152]);
    }
}

// ---------- featurize, 4-way split: wave w = grid level w (16ch) + FFM chans [w*16, w*16+16) ----------
template<int USE_WS, int LVL>
__device__ __forceinline__ void fz_level(const u16* __restrict__ gT,
                                         const float* __restrict__ gf,
                                         float x, float y, float z,
                                         u16* __restrict__ actw, int row)
{
    constexpr int S   = (LVL == 0) ? 16 : (LVL == 1) ? 32 : (LVL == 2) ? 64 : 96;
    constexpr int OFF = (LVL == 0) ? 0 : (LVL == 1) ? 65536 : (LVL == 2) ? 589824 : 4784128;
    constexpr int S3  = S * S * S;
    const float fS = (float)(S - 1);
    float px = fminf(fmaxf((x + 1.f) * 0.5f * fS, 0.f), fS);
    float py = fminf(fmaxf((y + 1.f) * 0.5f * fS, 0.f), fS);
    float pz = fminf(fmaxf((z + 1.f) * 0.5f * fS, 0.f), fS);
    int ix0 = (int)px, iy0 = (int)py, iz0 = (int)pz;
    float wx = px - (float)ix0, wy = py - (float)iy0, wz = pz - (float)iz0;
    int ix1 = min(ix0 + 1, S - 1), iy1 = min(iy0 + 1, S - 1), iz1 = min(iz0 + 1, S - 1);

    float f[16];
#pragma unroll
    for (int c = 0; c < 16; ++c) f[c] = 0.f;

#pragma unroll
    for (int cz = 0; cz < 2; ++cz) {
        int zz = cz ? iz1 : iz0;
        float wgtz = cz ? wz : (1.f - wz);
#pragma unroll
        for (int cy = 0; cy < 2; ++cy) {
            int yy = cy ? iy1 : iy0;
            float wgty = wgtz * (cy ? wy : (1.f - wy));
#pragma unroll
            for (int cx = 0; cx < 2; ++cx) {
                int xx = cx ? ix1 : ix0;
                float wgt = wgty * (cx ? wx : (1.f - wx));
                if (USE_WS) {
                    const uint4* p = (const uint4*)(gT + OFF + (size_t)(((zz * S) + yy) * S + xx) * 16);
                    uint4 a = p[0], b = p[1];
                    f[0]  += wgt * b2f((u16)(a.x & 0xffff));  f[1]  += wgt * b2f((u16)(a.x >> 16));
                    f[2]  += wgt * b2f((u16)(a.y & 0xffff));  f[3]  += wgt * b2f((u16)(a.y >> 16));
                    f[4]  += wgt * b2f((u16)(a.z & 0xffff));  f[5]  += wgt * b2f((u16)(a.z >> 16));
                    f[6]  += wgt * b2f((u16)(a.w & 0xffff));  f[7]  += wgt * b2f((u16)(a.w >> 16));
                    f[8]  += wgt * b2f((u16)(b.x & 0xffff));  f[9]  += wgt * b2f((u16)(b.x >> 16));
                    f[10] += wgt * b2f((u16)(b.y & 0xffff));  f[11] += wgt * b2f((u16)(b.y >> 16));
                    f[12] += wgt * b2f((u16)(b.z & 0xffff));  f[13] += wgt * b2f((u16)(b.z >> 16));
                    f[14] += wgt * b2f((u16)(b.w & 0xffff));  f[15] += wgt * b2f((u16)(b.w >> 16));
                } else {
                    size_t vox = (size_t)((zz * S) + yy) * S + xx;
#pragma unroll
                    for (int c = 0; c < 16; ++c)
                        f[c] += wgt * gf[(size_t)c * S3 + vox];
                }
            }
        }
    }
#pragma unroll
    for (int c = 0; c < 16; c += 4)
        store4(actw, row, LVL * 16 + c,
               fsilu(f[c]), fsilu(f[c + 1]), fsilu(f[c + 2]), fsilu(f[c + 3]));
}

template<int USE_WS, int HASB>
__device__ __forceinline__ void featurize4(const u16* __restrict__ gT, GridPtrs gp, int part,
                                           float x, float y, float z,
                                           const float* __restrict__ pe_w,
                                           const float* __restrict__ pe_b,
                                           u16* __restrict__ actw, int row)
{
    // part (= wave id) is wave-uniform: each wave takes exactly one branch.
    switch (part) {
        case 0:  fz_level<USE_WS, 0>(gT, gp.g[0], x, y, z, actw, row); break;
        case 1:  fz_level<USE_WS, 1>(gT, gp.g[1], x, y, z, actw, row); break;
        case 2:  fz_level<USE_WS, 2>(gT, gp.g[2], x, y, z, actw, row); break;
        default: fz_level<USE_WS, 3>(gT, gp.g[3], x, y, z, actw, row); break;
    }
    // FFM: sin(coords @ pe_w^T (+ b)) -> channels 64+part*16 .. 64+part*16+15
    const int f0 = part * 16;
#pragma unroll 4
    for (int fc = f0; fc < f0 + 16; fc += 4) {
        float s[4];
#pragma unroll
        for (int j = 0; j < 4; ++j) {
            int ch = fc + j;
            float a = x * pe_w[ch * 3 + 0] + y * pe_w[ch * 3 + 1] + z * pe_w[ch * 3 + 2];
            if (HASB) a += pe_b[ch];
            s[j] = fsin(a);
        }
        store4(actw, row, 64 + fc, s[0], s[1], s[2], s[3]);
    }
}

// ---------- per-wave 128x16 layer slice: wave w owns points w*16..w*16+15 (nt = w) ----------
__device__ __forceinline__ void loadB(const u16* actw, bf16x8 B[4], int row, int quad) {
#pragma unroll
    for (int kt = 0; kt < 4; ++kt)
        B[kt] = *(const bf16x8*)(actw + aidx(row, kt * 32 + quad * 8));
    ldsfence();   // pin loads BEFORE the in-place epilogue stores that follow
}

template<int USE_WS>
__device__ __forceinline__ bf16x8 loadA(const u16* WT, const float* Wf, int row, int chunk) {
    if (USE_WS) {
        return ((const bf16x8*)WT)[row * 16 + chunk];
    } else {
        const float4* p = (const float4*)(Wf + row * 128 + chunk * 8);
        float4 f0 = p[0], f1 = p[1];
        u32 w0 = (u32)f2b(f0.x) | ((u32)f2b(f0.y) << 16);
        u32 w1 = (u32)f2b(f0.z) | ((u32)f2b(f0.w) << 16);
        u32 w2 = (u32)f2b(f1.x) | ((u32)f2b(f1.y) << 16);
        u32 w3 = (u32)f2b(f1.z) | ((u32)f2b(f1.w) << 16);
        uint4 packed = make_uint4(w0, w1, w2, w3);
        bf16x8 r; __builtin_memcpy(&r, &packed, 16); return r;
    }
}

// mt loop unrolled only 2x: caps the compiler's A-load software pipeline at
// ~8 in-flight b128 loads (32 VGPRs) instead of 32 (128 VGPRs). Latency is
// hidden by TLP (4+ waves/SIMD), not per-wave pipelining — R2 showed the
// full-unroll pressure + launch_bounds min-waves cap caused 820 MB of
// scratch spill traffic.
template<int USE_WS, typename Epi>
__device__ __forceinline__ void gemm128(const u16* __restrict__ WT, const float* __restrict__ Wf,
                                        const bf16x8 B[4],
                                        int l16, int quad, Epi&& epi)
{
#pragma unroll 2
    for (int mt = 0; mt < 8; ++mt) {
        f32x4 acc = (f32x4){0.f, 0.f, 0.f, 0.f};
#pragma unroll
        for (int kt = 0; kt < 4; ++kt) {
            // A frag: W[mt*16 + (lane&15)][kt*32 + quad*8 .. +7]
            bf16x8 a = loadA<USE_WS>(WT, Wf, mt * 16 + l16, kt * 4 + quad);
            acc = __builtin_amdgcn_mfma_f32_16x16x32_bf16(a, B[kt], acc, 0, 0, 0);
        }
        epi(mt, acc);
    }
}

// ---------- fused main kernel: one block = 4 waves = 64 points ----------
// 256-thread blocks over ONE act tile + one tfp tile (32 KiB LDS -> 5 blocks/CU
// LDS cap). No launch_bounds min-waves arg: R2 proved the backend overshoots
// the cap (spilled to 64 VGPR / 8 waves-per-EU, 820 MB scratch traffic).
// Pressure is reduced structurally instead: tfp lives in LDS, mt unroll = 2.
// Wave w: featurizes grid-level w for all 64 points, then owns output slice
// nt = w (points w*16..w*16+15) in every GEMM -> B[4] (16 regs). In GEMM
// phases each wave touches only its own 16 act rows.
template<int USE_WS>
__global__ void __launch_bounds__(256)
dtn_main(const float* __restrict__ nc, const float* __restrict__ tauP,
         const float* __restrict__ phys, const u16* __restrict__ wsT,
         GridPtrs vgp, GridPtrs tgp,
         const float* __restrict__ vec_pe_w, const float* __restrict__ tau_pe_w,
         const float* __restrict__ tau_pe_b, const float* __restrict__ vscale,
         const float* __restrict__ map_w, const float* __restrict__ tau_mlp_w,
         const float* __restrict__ mlp_w, const float* __restrict__ tau_pars,
         const float* __restrict__ last_w, float* __restrict__ outP)
{
    __shared__ __align__(16) u16 actw[64 * 128];   // 16 KiB, one 64x128 bf16 tile
    __shared__ __align__(16) u16 tfpw[64 * 128];   // 16 KiB, tfp stash (was tfpPk[16] regs -> spilled)
    const int tid  = threadIdx.x;
    const int w    = tid >> 6;            // wave id = featurize part = gemm nt
    const int lane = tid & 63;            // featurize row (point-in-block)
    const int quad = lane >> 4, l16 = lane & 15;
    const int row  = w * 16 + l16;        // gemm-phase act row (wave-private)

    const int pBase = blockIdx.x * 64;
    const int fzPt  = pBase + lane;       // point this thread featurizes
    const int myPt  = pBase + row;        // point this thread's gemm/head slice owns

    float cx = nc[fzPt * 3 + 0];
    float cy = nc[fzPt * 3 + 1];
    float cz = nc[fzPt * 3 + 2];
    float tauv = tauP[myPt];

    const u16* wsVec = wsT;
    const u16* wsTau = wsT + WS_TAU;
    const u16* wMap  = wsT + WS_MAP;
    const u16* wTmlp = wsT + WS_TMLP;
    const u16* wMlp  = wsT + WS_MLP;

    // ---- tau featurize (4-way level split across waves) ----
    featurize4<USE_WS, 1>(wsTau, tgp, w, cx, cy, cz, tau_pe_w, tau_pe_b, actw, lane);
    __syncthreads();

    // ---- tfp = tau_features @ tau_mlp_w^T -> LDS stash (bf16, C-frag positions) ----
    bf16x8 B[4];
    loadB(actw, B, row, quad);
    gemm128<USE_WS>(wTmlp, tau_mlp_w, B, l16, quad, [&](int mt, f32x4 acc) {
        int cb = mt * 16 + quad * 4;
        store4(tfpw, row, cb, acc[0], acc[1], acc[2], acc[3]);
    });
    __syncthreads();

    // ---- vec featurize (overwrite act) ----
    featurize4<USE_WS, 0>(wsVec, vgp, w, cx, cy, cz, vec_pe_w, (const float*)nullptr, actw, lane);
    __syncthreads();

    // ---- vec_map layer 0: act = silu(act @ W0^T) ----
    loadB(actw, B, row, quad);
    gemm128<USE_WS>(wMap, map_w, B, l16, quad, [&](int mt, f32x4 acc) {
        int cb = mt * 16 + quad * 4;
        store4(actw, row, cb, fsilu(acc[0]), fsilu(acc[1]), fsilu(acc[2]), fsilu(acc[3]));
    });
    __syncthreads();

    // ---- vec_map layer 1 fused with out-init: act = tanh(tau * vscale * silu(.)) ----
    loadB(actw, B, row, quad);
    gemm128<USE_WS>(wMap + 128 * 128, map_w + 128 * 128, B, l16, quad, [&](int mt, f32x4 acc) {
        int cb = mt * 16 + quad * 4;
        float4 vs = *(const float4*)(vscale + cb);
        store4(actw, row, cb,
               ftanh(tauv * vs.x * fsilu(acc[0])), ftanh(tauv * vs.y * fsilu(acc[1])),
               ftanh(tauv * vs.z * fsilu(acc[2])), ftanh(tauv * vs.w * fsilu(acc[3])));
    });
    __syncthreads();

    // ---- 3 residual layers: out += tanh(tau*tp) * silu(out @ Wv^T [* tfp @ idx0]) ----
#pragma unroll
    for (int idx = 0; idx < 3; ++idx) {
        loadB(actw, B, row, quad);
        gemm128<USE_WS>(wMlp + idx * 128 * 128, mlp_w + idx * 128 * 128, B, l16, quad,
                        [&](int mt, f32x4 acc) {
            int cb = mt * 16 + quad * 4;
            float4 tp = *(const float4*)(tau_pars + idx * 128 + cb);
            uint2 old = *(const uint2*)(actw + aidx(row, cb));
            float h0 = acc[0], h1 = acc[1], h2 = acc[2], h3 = acc[3];
            if (idx == 0) {
                uint2 tf = *(const uint2*)(tfpw + aidx(row, cb));
                h0 *= b2f((u16)(tf.x & 0xffff));
                h1 *= b2f((u16)(tf.x >> 16));
                h2 *= b2f((u16)(tf.y & 0xffff));
                h3 *= b2f((u16)(tf.y >> 16));
            }
            float n0 = b2f((u16)(old.x & 0xffff)) + ftanh(tauv * tp.x) * fsilu(h0);
            float n1 = b2f((u16)(old.x >> 16))    + ftanh(tauv * tp.y) * fsilu(h1);
            float n2 = b2f((u16)(old.y & 0xffff)) + ftanh(tauv * tp.z) * fsilu(h2);
            float n3 = b2f((u16)(old.y >> 16))    + ftanh(tauv * tp.w) * fsilu(h3);
            store4(actw, row, cb, n0, n1, n2, n3);
        });
        __syncthreads();
    }

    // ---- head: out = physical + act_row @ last_w^T  (3x128); lane does point `row`,
    //      k-segment quad*32..+31, then 2-step shfl_xor reduce across quads ----
    float a0 = 0.f, a1 = 0.f, a2 = 0.f;
#pragma unroll
    for (int c8 = 0; c8 < 4; ++c8) {
        int kb = quad * 32 + c8 * 8;
        bf16x8 v = *(const bf16x8*)(actw + aidx(row, kb));
        const u16* vp = (const u16*)&v;
#pragma unroll
        for (int j = 0; j < 8; ++j) {
            float av = b2f(vp[j]);
            int k = kb + j;
            a0 += av * last_w[0 * 128 + k];
            a1 += av * last_w[1 * 128 + k];
            a2 += av * last_w[2 * 128 + k];
        }
    }
    a0 += __shfl_xor(a0, 16); a0 += __shfl_xor(a0, 32);
    a1 += __shfl_xor(a1, 16); a1 += __shfl_xor(a1, 32);
    a2 += __shfl_xor(a2, 16); a2 += __shfl_xor(a2, 32);
    if (quad == 0) {
        outP[myPt * 3 + 0] = phys[myPt * 3 + 0] + a0;
        outP[myPt * 3 + 1] = phys[myPt * 3 + 1] + a1;
        outP[myPt * 3 + 2] = phys[myPt * 3 + 2] + a2;
    }
}

// ---------- launch ----------
extern "C" void kernel_launch(void* const* d_in, const int* in_sizes, int n_in,
                              void* d_out, int out_size, void* d_ws, size_t ws_size,
                              hipStream_t stream)
{
    // Supports both documented dict order (grids interleaved vec_g0,tau_g0,...)
    // and reference-signature order (vec_g0..3 then tau_g0..3). Slots 0-2 and
    // 11-19 are identical in both. Detect via in_sizes[4]: 65536 -> interleaved.
    const float* phys     = (const float*)d_in[0];
    const float* nc       = (const float*)d_in[1];
    const float* tau      = (const float*)d_in[2];
    GridPtrs vgp, tgp;
    bool interleaved = (in_sizes[4] == 65536);
    for (int l = 0; l < 4; ++l) {
        if (interleaved) {
            vgp.g[l] = (const float*)d_in[3 + 2 * l];
            tgp.g[l] = (const float*)d_in[4 + 2 * l];
        } else {
            vgp.g[l] = (const float*)d_in[3 + l];
            tgp.g[l] = (const float*)d_in[7 + l];
        }
    }
    const float* vec_pe_w = (const float*)d_in[11];
    const float* tau_pe_w = (const float*)d_in[12];
    const float* tau_pe_b = (const float*)d_in[13];
    const float* vscale   = (const float*)d_in[14];
    const float* map_w    = (const float*)d_in[15];
    const float* tau_mlp  = (const float*)d_in[16];
    const float* mlp_w    = (const float*)d_in[17];
    const float* tau_pars = (const float*)d_in[18];
    const float* last_w   = (const float*)d_in[19];
    u16* wsT = (u16*)d_ws;

    bool useWs = (ws_size >= WS_TOTAL_BYTES);
    if (useWs) {
        PrepArgs pa;
        for (int l = 0; l < 4; ++l) { pa.vg[l] = vgp.g[l]; pa.tg[l] = tgp.g[l]; }
        pa.map_w = map_w; pa.tmlp = tau_mlp; pa.mlp = mlp_w; pa.ws = wsT;
        dtn_prep<<<PREP_VOXB + 384, 256, 0, stream>>>(pa);
        dtn_main<1><<<N_PTS / 64, 256, 0, stream>>>(nc, tau, phys, wsT, vgp, tgp,
                                                    vec_pe_w, tau_pe_w, tau_pe_b, vscale,
                                                    map_w, tau_mlp, mlp_w, tau_pars, last_w,
                                                    (float*)d_out);
    } else {
        dtn_main<0><<<N_PTS / 64, 256, 0, stream>>>(nc, tau, phys, wsT, vgp, tgp,
                                                    vec_pe_w, tau_pe_w, tau_pe_b, vscale,
                                                    map_w, tau_mlp, mlp_w, tau_pars, last_w,
                                                    (float*)d_out);
    }
}

// Round 4
// 791.295 us; speedup vs baseline: 1.6205x; 1.4298x over previous
//
#include <hip/hip_runtime.h>
#include <hip/hip_bf16.h>

typedef unsigned short u16;
typedef unsigned int   u32;
typedef short bf16x8 __attribute__((ext_vector_type(8)));   // 8 bf16 = 4 VGPRs (MFMA A/B frag)
typedef float f32x4  __attribute__((ext_vector_type(4)));   // MFMA C/D frag

#define N_PTS   524288

// ws layout (u16 element offsets). Grids stored channel-last bf16 (voxel-major, 16ch).
#define WS_TAU   18939904
#define WS_MAP   37879808
#define WS_TMLP  37912576
#define WS_MLP   37928960
#define WS_TOTAL_BYTES (37978112ULL * 2ULL)

// Compiler memory fence: keeps differently-typed LDS reads/writes of the act
// tile from being reordered (TBAA insurance; zero runtime cost).
__device__ __forceinline__ void ldsfence() { __asm__ __volatile__("" ::: "memory"); }

// ---------- bf16 / fast-math helpers ----------
__device__ __forceinline__ float b2f(u16 b) {
    u32 u = ((u32)b) << 16; float f; __builtin_memcpy(&f, &u, 4); return f;
}
__device__ __forceinline__ u16 f2b(float f) {
    u32 u; __builtin_memcpy(&u, &f, 4);
    u32 r = (u + 0x7FFFu + ((u >> 16) & 1u)) >> 16;   // RNE
    return (u16)r;
}
// v_rcp_f32: ~1ulp approx — fine at our 2% tolerance, replaces ~10-inst IEEE div
__device__ __forceinline__ float frcp(float x) { return __builtin_amdgcn_rcpf(x); }
__device__ __forceinline__ float fsilu(float x) { return x * frcp(1.f + __expf(-x)); }
__device__ __forceinline__ float ftanh(float x) {
    float e = __expf(2.f * x);
    return 1.f - 2.f * frcp(e + 1.f);
}
// v_sin_f32 takes revolutions; |arg| <= ~7 rad = 1.2 rev here (well in range)
__device__ __forceinline__ float fsin(float a) {
    return __builtin_amdgcn_sinf(a * 0.15915494309189535f);
}

// act LDS index, XOR swizzle on 16B chunks (breaks 256B power-of-2 row stride).
// Any access within one 8-elem chunk (4- or 8-aligned groups) stays contiguous.
__device__ __forceinline__ int aidx(int row, int ch) {
    return (row << 7) + ((((ch >> 3) ^ (row & 7))) << 3) + (ch & 7);
}

__device__ __forceinline__ void store4(u16* actw, int row, int ch,
                                       float v0, float v1, float v2, float v3) {
    u32 lo = (u32)f2b(v0) | ((u32)f2b(v1) << 16);
    u32 hi = (u32)f2b(v2) | ((u32)f2b(v3) << 16);
    *(uint2*)(actw + aidx(row, ch)) = make_uint2(lo, hi);   // ds_write_b64
}

struct GridPtrs { const float* g[4]; };

// ---------- fused prep: 8 grid transposes (f32 C-major -> bf16 channel-last) + 3 weight cvts ----------
struct PrepArgs {
    const float* vg[4]; const float* tg[4];
    const float* map_w; const float* tmlp; const float* mlp;
    u16* ws;
};
#define PREP_VOXB 9248   // 2*1183744 / 256
__global__ void __launch_bounds__(256) dtn_prep(PrepArgs p) {
    int b = blockIdx.x;
    if (b < PREP_VOXB) {
        int v = b * 256 + threadIdx.x;          // global voxel id over both grid sets
        int set = (v >= 1183744) ? 1 : 0;
        int lv = v - set * 1183744;
        int l, base, S3, off;
        if      (lv <   4096) { l = 0; base = 0;      S3 = 4096;   off = 0;       }
        else if (lv <  36864) { l = 1; base = 4096;   S3 = 32768;  off = 65536;   }
        else if (lv < 299008) { l = 2; base = 36864;  S3 = 262144; off = 589824;  }
        else                  { l = 3; base = 299008; S3 = 884736; off = 4784128; }
        int vox = lv - base;
        const float* src = set ? p.tg[l] : p.vg[l];
        u16* dst = p.ws + (set ? WS_TAU : 0) + off + (size_t)vox * 16;
        u32 packed[8];
#pragma unroll
        for (int c = 0; c < 8; ++c) {
            u32 lo = f2b(src[(2 * c) * S3 + vox]);
            u32 hi = f2b(src[(2 * c + 1) * S3 + vox]);
            packed[c] = lo | (hi << 16);
        }
        uint4* d = (uint4*)dst;
        d[0] = make_uint4(packed[0], packed[1], packed[2], packed[3]);
        d[1] = make_uint4(packed[4], packed[5], packed[6], packed[7]);
    } else {
        int i = (b - PREP_VOXB) * 256 + threadIdx.x;   // weights: 98304 elems total
        if (i < 32768)      p.ws[WS_MAP  + i]          = f2b(p.map_w[i]);
        else if (i < 49152) p.ws[WS_TMLP + (i - 32768)] = f2b(p.tmlp[i - 32768]);
        else if (i < 98304) p.ws[WS_MLP  + (i - 49152)] = f2b(p.mlp[i - 49152]);
    }
}

// ---------- featurize, intra-wave split: lane (h = lane>>5, pt = lane&31) ----------
// Each point is handled by TWO lanes: h=0 -> grid levels 0,1 (ch 0..31) + FFM ch 64..95;
// h=1 -> grid levels 2,3 (ch 32..63) + FFM ch 96..127. Branchless in h (level index
// is a per-lane runtime value -> cndmask selects, no exec-mask divergence, so the
// two halves' gathers pipeline in parallel within the wave).
template<int USE_WS, int HASB>
__device__ __forceinline__ void featurize32(const u16* __restrict__ gT, GridPtrs gp, int h,
                                            float x, float y, float z,
                                            const float* __restrict__ pe_w,
                                            const float* __restrict__ pe_b,
                                            u16* __restrict__ actw, int row)
{
#pragma unroll
    for (int lv2 = 0; lv2 < 2; ++lv2) {
        const int l = h * 2 + lv2;                 // lane-varying level index
        const int S   = (l == 0) ? 16 : (l == 1) ? 32 : (l == 2) ? 64 : 96;
        const int OFF = (l == 0) ? 0  : (l == 1) ? 65536 : (l == 2) ? 589824 : 4784128;
        const float fS = (float)(S - 1);
        float px = fminf(fmaxf((x + 1.f) * 0.5f * fS, 0.f), fS);
        float py = fminf(fmaxf((y + 1.f) * 0.5f * fS, 0.f), fS);
        float pz = fminf(fmaxf((z + 1.f) * 0.5f * fS, 0.f), fS);
        int ix0 = (int)px, iy0 = (int)py, iz0 = (int)pz;
        float wx = px - (float)ix0, wy = py - (float)iy0, wz = pz - (float)iz0;
        int ix1 = min(ix0 + 1, S - 1), iy1 = min(iy0 + 1, S - 1), iz1 = min(iz0 + 1, S - 1);
        // strength-reduced corner addressing: base + {0,dx} + {0,dy} + {0,dz}
        int dx = ix1 - ix0;
        int dy = (iy1 - iy0) * S;
        int dz = (iz1 - iz0) * S * S;
        int i000 = (iz0 * S + iy0) * S + ix0;

        float f[16];
#pragma unroll
        for (int c = 0; c < 16; ++c) f[c] = 0.f;

#pragma unroll
        for (int cz = 0; cz < 2; ++cz) {
            float wgtz = cz ? wz : (1.f - wz);
            int iz = cz ? dz : 0;
#pragma unroll
            for (int cy = 0; cy < 2; ++cy) {
                float wgty = wgtz * (cy ? wy : (1.f - wy));
                int izy = iz + (cy ? dy : 0);
#pragma unroll
                for (int cx = 0; cx < 2; ++cx) {
                    float wgt = wgty * (cx ? wx : (1.f - wx));
                    int idx = i000 + izy + (cx ? dx : 0);
                    if (USE_WS) {
                        const uint4* p = (const uint4*)(gT + OFF + (size_t)idx * 16);
                        uint4 a = p[0], b = p[1];
                        f[0]  += wgt * b2f((u16)(a.x & 0xffff));  f[1]  += wgt * b2f((u16)(a.x >> 16));
                        f[2]  += wgt * b2f((u16)(a.y & 0xffff));  f[3]  += wgt * b2f((u16)(a.y >> 16));
                        f[4]  += wgt * b2f((u16)(a.z & 0xffff));  f[5]  += wgt * b2f((u16)(a.z >> 16));
                        f[6]  += wgt * b2f((u16)(a.w & 0xffff));  f[7]  += wgt * b2f((u16)(a.w >> 16));
                        f[8]  += wgt * b2f((u16)(b.x & 0xffff));  f[9]  += wgt * b2f((u16)(b.x >> 16));
                        f[10] += wgt * b2f((u16)(b.y & 0xffff));  f[11] += wgt * b2f((u16)(b.y >> 16));
                        f[12] += wgt * b2f((u16)(b.z & 0xffff));  f[13] += wgt * b2f((u16)(b.z >> 16));
                        f[14] += wgt * b2f((u16)(b.w & 0xffff));  f[15] += wgt * b2f((u16)(b.w >> 16));
                    } else {
                        const float* gf = (l == 0) ? gp.g[0] : (l == 1) ? gp.g[1]
                                        : (l == 2) ? gp.g[2] : gp.g[3];
                        const int S3 = S * S * S;
#pragma unroll
                        for (int c = 0; c < 16; ++c)
                            f[c] += wgt * gf[(size_t)c * S3 + idx];
                    }
                }
            }
        }
#pragma unroll
        for (int c = 0; c < 16; c += 4)
            store4(actw, row, l * 16 + c,
                   fsilu(f[c]), fsilu(f[c + 1]), fsilu(f[c + 2]), fsilu(f[c + 3]));
    }
    // FFM: sin(coords @ pe_w^T (+ b)) -> channels 64 + h*32 .. 64 + h*32 + 31
    const int f0 = h * 32;
#pragma unroll 4
    for (int fc = 0; fc < 32; fc += 4) {
        float s[4];
#pragma unroll
        for (int j = 0; j < 4; ++j) {
            int ch = f0 + fc + j;
            float a = x * pe_w[ch * 3 + 0] + y * pe_w[ch * 3 + 1] + z * pe_w[ch * 3 + 2];
            if (HASB) a += pe_b[ch];
            s[j] = fsin(a);
        }
        store4(actw, row, 64 + f0 + fc, s[0], s[1], s[2], s[3]);
    }
}

// ---------- per-wave 128x32 layer: D(out_ch, pt) = W(128x128) x act^T, 2 nt tiles ----------
__device__ __forceinline__ void loadB(const u16* actw, bf16x8 B[2][4], int l16, int quad) {
#pragma unroll
    for (int nt = 0; nt < 2; ++nt)
#pragma unroll
        for (int kt = 0; kt < 4; ++kt)
            B[nt][kt] = *(const bf16x8*)(actw + aidx(nt * 16 + l16, kt * 32 + quad * 8));
    ldsfence();   // pin loads BEFORE the in-place epilogue stores that follow
}

template<int USE_WS>
__device__ __forceinline__ bf16x8 loadA(const u16* WT, const float* Wf, int row, int chunk) {
    if (USE_WS) {
        return ((const bf16x8*)WT)[row * 16 + chunk];
    } else {
        const float4* p = (const float4*)(Wf + row * 128 + chunk * 8);
        float4 f0 = p[0], f1 = p[1];
        u32 w0 = (u32)f2b(f0.x) | ((u32)f2b(f0.y) << 16);
        u32 w1 = (u32)f2b(f0.z) | ((u32)f2b(f0.w) << 16);
        u32 w2 = (u32)f2b(f1.x) | ((u32)f2b(f1.y) << 16);
        u32 w3 = (u32)f2b(f1.z) | ((u32)f2b(f1.w) << 16);
        uint4 packed = make_uint4(w0, w1, w2, w3);
        bf16x8 r; __builtin_memcpy(&r, &packed, 16); return r;
    }
}

// mt unroll 2: caps the A-load pipeline at ~8 in-flight b128 loads (32 VGPRs)
// — full unroll's 128-reg pipeline is what pushed R0 to 224 VGPR.
template<int USE_WS, typename Epi>
__device__ __forceinline__ void gemm128(const u16* __restrict__ WT, const float* __restrict__ Wf,
                                        const bf16x8 B[2][4],
                                        int l16, int quad, Epi&& epi)
{
#pragma unroll 2
    for (int mt = 0; mt < 8; ++mt) {
        f32x4 acc[2];
#pragma unroll
        for (int nt = 0; nt < 2; ++nt) acc[nt] = (f32x4){0.f, 0.f, 0.f, 0.f};
#pragma unroll
        for (int kt = 0; kt < 4; ++kt) {
            // A frag: W[mt*16 + (lane&15)][kt*32 + quad*8 .. +7]
            bf16x8 a = loadA<USE_WS>(WT, Wf, mt * 16 + l16, kt * 4 + quad);
#pragma unroll
            for (int nt = 0; nt < 2; ++nt)
                acc[nt] = __builtin_amdgcn_mfma_f32_16x16x32_bf16(a, B[nt][kt], acc[nt], 0, 0, 0);
        }
#pragma unroll
        for (int nt = 0; nt < 2; ++nt) epi(mt, nt, acc[nt]);
    }
}

// ---------- fused main kernel: one block = one wave = 32 points ----------
// R0's single-wave structure (zero barrier cost, no weight-redundancy beyond 2x,
// homogeneous lanes) with the per-wave tile halved to lift both occupancy caps:
// LDS 8 KiB/block (was 16) and VGPR ~150 (B[2][4]=32, tfpPk[32]; was 64+64 -> 224).
// Target 3 waves/SIMD (12/CU) vs R0's 2 (8/CU). R2/R3 showed multi-wave shared
// tiles lose to barriers + featurize imbalance — this keeps everything wave-local.
template<int USE_WS>
__global__ void __launch_bounds__(64)
dtn_main(const float* __restrict__ nc, const float* __restrict__ tauP,
         const float* __restrict__ phys, const u16* __restrict__ wsT,
         GridPtrs vgp, GridPtrs tgp,
         const float* __restrict__ vec_pe_w, const float* __restrict__ tau_pe_w,
         const float* __restrict__ tau_pe_b, const float* __restrict__ vscale,
         const float* __restrict__ map_w, const float* __restrict__ tau_mlp_w,
         const float* __restrict__ mlp_w, const float* __restrict__ tau_pars,
         const float* __restrict__ last_w, float* __restrict__ outP)
{
    __shared__ __align__(16) u16 actw[32 * 128];   // 8 KiB, one 32x128 bf16 tile
    const int lane = threadIdx.x;
    const int h    = lane >> 5;           // featurize half (levels 2h,2h+1 + 32 FFM)
    const int pt   = lane & 31;           // featurize row (point-in-block)
    const int quad = lane >> 4, l16 = lane & 15;

    const int pBase = blockIdx.x * 32;
    const int fzPt  = pBase + pt;         // point this lane featurizes (2 lanes/pt)

    float cx = nc[fzPt * 3 + 0];
    float cy = nc[fzPt * 3 + 1];
    float cz = nc[fzPt * 3 + 2];

    float tauv[2];
#pragma unroll
    for (int nt = 0; nt < 2; ++nt) tauv[nt] = tauP[pBase + nt * 16 + l16];

    const u16* wsVec = wsT;
    const u16* wsTau = wsT + WS_TAU;
    const u16* wMap  = wsT + WS_MAP;
    const u16* wTmlp = wsT + WS_TMLP;
    const u16* wMlp  = wsT + WS_MLP;

    // ---- tau featurize ----
    featurize32<USE_WS, 1>(wsTau, tgp, h, cx, cy, cz, tau_pe_w, tau_pe_b, actw, pt);
    __syncthreads();

    // ---- tfp = tau_features @ tau_mlp_w^T  (packed bf16 in regs, C-frag layout) ----
    bf16x8 B[2][4];
    loadB(actw, B, l16, quad);
    u32 tfpPk[32];
    gemm128<USE_WS>(wTmlp, tau_mlp_w, B, l16, quad, [&](int mt, int nt, f32x4 acc) {
        int base = (mt * 2 + nt) * 2;
        tfpPk[base + 0] = (u32)f2b(acc[0]) | ((u32)f2b(acc[1]) << 16);
        tfpPk[base + 1] = (u32)f2b(acc[2]) | ((u32)f2b(acc[3]) << 16);
    });
    __syncthreads();

    // ---- vec featurize (overwrite act) ----
    featurize32<USE_WS, 0>(wsVec, vgp, h, cx, cy, cz, vec_pe_w, (const float*)nullptr, actw, pt);
    __syncthreads();

    // ---- vec_map layer 0: act = silu(act @ W0^T) ----
    loadB(actw, B, l16, quad);
    gemm128<USE_WS>(wMap, map_w, B, l16, quad, [&](int mt, int nt, f32x4 acc) {
        int cb = mt * 16 + quad * 4, prow = nt * 16 + l16;
        store4(actw, prow, cb, fsilu(acc[0]), fsilu(acc[1]), fsilu(acc[2]), fsilu(acc[3]));
    });
    __syncthreads();

    // ---- vec_map layer 1 fused with out-init: act = tanh(tau * vscale * silu(.)) ----
    loadB(actw, B, l16, quad);
    gemm128<USE_WS>(wMap + 128 * 128, map_w + 128 * 128, B, l16, quad, [&](int mt, int nt, f32x4 acc) {
        int cb = mt * 16 + quad * 4, prow = nt * 16 + l16;
        float t = tauv[nt];
        float4 vs = *(const float4*)(vscale + cb);
        store4(actw, prow, cb,
               ftanh(t * vs.x * fsilu(acc[0])), ftanh(t * vs.y * fsilu(acc[1])),
               ftanh(t * vs.z * fsilu(acc[2])), ftanh(t * vs.w * fsilu(acc[3])));
    });
    __syncthreads();

    // ---- 3 residual layers: out += tanh(tau*tp) * silu(out @ Wv^T [* tfp @ idx0]) ----
#pragma unroll
    for (int idx = 0; idx < 3; ++idx) {
        loadB(actw, B, l16, quad);
        gemm128<USE_WS>(wMlp + idx * 128 * 128, mlp_w + idx * 128 * 128, B, l16, quad,
                        [&](int mt, int nt, f32x4 acc) {
            int cb = mt * 16 + quad * 4, prow = nt * 16 + l16;
            float t = tauv[nt];
            float4 tp = *(const float4*)(tau_pars + idx * 128 + cb);
            uint2 old = *(const uint2*)(actw + aidx(prow, cb));
            float h0 = acc[0], h1 = acc[1], h2 = acc[2], h3 = acc[3];
            if (idx == 0) {
                int base = (mt * 2 + nt) * 2;
                h0 *= b2f((u16)(tfpPk[base] & 0xffff));
                h1 *= b2f((u16)(tfpPk[base] >> 16));
                h2 *= b2f((u16)(tfpPk[base + 1] & 0xffff));
                h3 *= b2f((u16)(tfpPk[base + 1] >> 16));
            }
            float n0 = b2f((u16)(old.x & 0xffff)) + ftanh(t * tp.x) * fsilu(h0);
            float n1 = b2f((u16)(old.x >> 16))    + ftanh(t * tp.y) * fsilu(h1);
            float n2 = b2f((u16)(old.y & 0xffff)) + ftanh(t * tp.z) * fsilu(h2);
            float n3 = b2f((u16)(old.y >> 16))    + ftanh(t * tp.w) * fsilu(h3);
            store4(actw, prow, cb, n0, n1, n2, n3);
        });
        __syncthreads();
    }

    // ---- head: out = physical + act_row @ last_w^T  (3x128); 2 lanes per point,
    //      lane h covers k = h*64 .. h*64+63, then one shfl_xor(32) reduce ----
    float a0 = 0.f, a1 = 0.f, a2 = 0.f;
#pragma unroll
    for (int c8 = 0; c8 < 8; ++c8) {
        int kb = h * 64 + c8 * 8;
        bf16x8 v = *(const bf16x8*)(actw + aidx(pt, kb));
        const u16* vp = (const u16*)&v;
#pragma unroll
        for (int j = 0; j < 8; ++j) {
            float av = b2f(vp[j]);
            int k = kb + j;
            a0 += av * last_w[0 * 128 + k];
            a1 += av * last_w[1 * 128 + k];
            a2 += av * last_w[2 * 128 + k];
        }
    }
    a0 += __shfl_xor(a0, 32);
    a1 += __shfl_xor(a1, 32);
    a2 += __shfl_xor(a2, 32);
    if (h == 0) {
        outP[fzPt * 3 + 0] = phys[fzPt * 3 + 0] + a0;
        outP[fzPt * 3 + 1] = phys[fzPt * 3 + 1] + a1;
        outP[fzPt * 3 + 2] = phys[fzPt * 3 + 2] + a2;
    }
}

// ---------- launch ----------
extern "C" void kernel_launch(void* const* d_in, const int* in_sizes, int n_in,
                              void* d_out, int out_size, void* d_ws, size_t ws_size,
                              hipStream_t stream)
{
    // Supports both documented dict order (grids interleaved vec_g0,tau_g0,...)
    // and reference-signature order (vec_g0..3 then tau_g0..3). Slots 0-2 and
    // 11-19 are identical in both. Detect via in_sizes[4]: 65536 -> interleaved.
    const float* phys     = (const float*)d_in[0];
    const float* nc       = (const float*)d_in[1];
    const float* tau      = (const float*)d_in[2];
    GridPtrs vgp, tgp;
    bool interleaved = (in_sizes[4] == 65536);
    for (int l = 0; l < 4; ++l) {
        if (interleaved) {
            vgp.g[l] = (const float*)d_in[3 + 2 * l];
            tgp.g[l] = (const float*)d_in[4 + 2 * l];
        } else {
            vgp.g[l] = (const float*)d_in[3 + l];
            tgp.g[l] = (const float*)d_in[7 + l];
        }
    }
    const float* vec_pe_w = (const float*)d_in[11];
    const float* tau_pe_w = (const float*)d_in[12];
    const float* tau_pe_b = (const float*)d_in[13];
    const float* vscale   = (const float*)d_in[14];
    const float* map_w    = (const float*)d_in[15];
    const float* tau_mlp  = (const float*)d_in[16];
    const float* mlp_w    = (const float*)d_in[17];
    const float* tau_pars = (const float*)d_in[18];
    const float* last_w   = (const float*)d_in[19];
    u16* wsT = (u16*)d_ws;

    bool useWs = (ws_size >= WS_TOTAL_BYTES);
    if (useWs) {
        PrepArgs pa;
        for (int l = 0; l < 4; ++l) { pa.vg[l] = vgp.g[l]; pa.tg[l] = tgp.g[l]; }
        pa.map_w = map_w; pa.tmlp = tau_mlp; pa.mlp = mlp_w; pa.ws = wsT;
        dtn_prep<<<PREP_VOXB + 384, 256, 0, stream>>>(pa);
        dtn_main<1><<<N_PTS / 32, 64, 0, stream>>>(nc, tau, phys, wsT, vgp, tgp,
                                                   vec_pe_w, tau_pe_w, tau_pe_b, vscale,
                                                   map_w, tau_mlp, mlp_w, tau_pars, last_w,
                                                   (float*)d_out);
    } else {
        dtn_main<0><<<N_PTS / 32, 64, 0, stream>>>(nc, tau, phys, wsT, vgp, tgp,
                                                   vec_pe_w, tau_pe_w, tau_pe_b, vscale,
                                                   map_w, tau_mlp, mlp_w, tau_pars, last_w,
                                                   (float*)d_out);
    }
}

// Round 5
// 768.036 us; speedup vs baseline: 1.6696x; 1.0303x over previous
//
#include <hip/hip_runtime.h>
#include <hip/hip_bf16.h>

typedef unsigned short u16;
typedef unsigned int   u32;
typedef short bf16x8 __attribute__((ext_vector_type(8)));   // 8 bf16 = 4 VGPRs (MFMA A/B frag)
typedef float f32x4  __attribute__((ext_vector_type(4)));   // MFMA C/D frag

#define N_PTS   524288

// ws layout (u16 element offsets). Grids stored channel-last bf16 (voxel-major, 16ch).
#define WS_TAU   18939904
#define WS_MAP   37879808
#define WS_TMLP  37912576
#define WS_MLP   37928960
#define WS_TOTAL_BYTES (37978112ULL * 2ULL)

// Compiler memory fence: keeps differently-typed LDS reads/writes of the act
// tile from being reordered (TBAA insurance; zero runtime cost).
__device__ __forceinline__ void ldsfence() { __asm__ __volatile__("" ::: "memory"); }

// ---------- bf16 / fast-math helpers ----------
__device__ __forceinline__ float b2f(u16 b) {
    u32 u = ((u32)b) << 16; float f; __builtin_memcpy(&f, &u, 4); return f;
}
__device__ __forceinline__ u16 f2b(float f) {
    u32 u; __builtin_memcpy(&u, &f, 4);
    u32 r = (u + 0x7FFFu + ((u >> 16) & 1u)) >> 16;   // RNE
    return (u16)r;
}
// v_rcp_f32: ~1ulp approx — fine at our 2% tolerance, replaces ~10-inst IEEE div
__device__ __forceinline__ float frcp(float x) { return __builtin_amdgcn_rcpf(x); }
__device__ __forceinline__ float fsilu(float x) { return x * frcp(1.f + __expf(-x)); }
__device__ __forceinline__ float ftanh(float x) {
    float e = __expf(2.f * x);
    return 1.f - 2.f * frcp(e + 1.f);
}
// v_sin_f32 takes revolutions; |arg| <= ~7 rad = 1.2 rev here (well in range)
__device__ __forceinline__ float fsin(float a) {
    return __builtin_amdgcn_sinf(a * 0.15915494309189535f);
}

// act LDS index, XOR swizzle on 16B chunks (breaks 256B power-of-2 row stride).
// Any access within one 8-elem chunk (4- or 8-aligned groups) stays contiguous.
__device__ __forceinline__ int aidx(int row, int ch) {
    return (row << 7) + ((((ch >> 3) ^ (row & 7))) << 3) + (ch & 7);
}

__device__ __forceinline__ void store4(u16* actw, int row, int ch,
                                       float v0, float v1, float v2, float v3) {
    u32 lo = (u32)f2b(v0) | ((u32)f2b(v1) << 16);
    u32 hi = (u32)f2b(v2) | ((u32)f2b(v3) << 16);
    *(uint2*)(actw + aidx(row, ch)) = make_uint2(lo, hi);   // ds_write_b64
}

struct GridPtrs { const float* g[4]; };

// ---------- fused prep: 8 grid transposes (f32 C-major -> bf16 channel-last) + 3 weight cvts ----------
struct PrepArgs {
    const float* vg[4]; const float* tg[4];
    const float* map_w; const float* tmlp; const float* mlp;
    u16* ws;
};
#define PREP_VOXB 9248   // 2*1183744 / 256
__global__ void __launch_bounds__(256) dtn_prep(PrepArgs p) {
    int b = blockIdx.x;
    if (b < PREP_VOXB) {
        int v = b * 256 + threadIdx.x;          // global voxel id over both grid sets
        int set = (v >= 1183744) ? 1 : 0;
        int lv = v - set * 1183744;
        int l, base, S3, off;
        if      (lv <   4096) { l = 0; base = 0;      S3 = 4096;   off = 0;       }
        else if (lv <  36864) { l = 1; base = 4096;   S3 = 32768;  off = 65536;   }
        else if (lv < 299008) { l = 2; base = 36864;  S3 = 262144; off = 589824;  }
        else                  { l = 3; base = 299008; S3 = 884736; off = 4784128; }
        int vox = lv - base;
        const float* src = set ? p.tg[l] : p.vg[l];
        u16* dst = p.ws + (set ? WS_TAU : 0) + off + (size_t)vox * 16;
        u32 packed[8];
#pragma unroll
        for (int c = 0; c < 8; ++c) {
            u32 lo = f2b(src[(2 * c) * S3 + vox]);
            u32 hi = f2b(src[(2 * c + 1) * S3 + vox]);
            packed[c] = lo | (hi << 16);
        }
        uint4* d = (uint4*)dst;
        d[0] = make_uint4(packed[0], packed[1], packed[2], packed[3]);
        d[1] = make_uint4(packed[4], packed[5], packed[6], packed[7]);
    } else {
        int i = (b - PREP_VOXB) * 256 + threadIdx.x;   // weights: 98304 elems total
        if (i < 32768)      p.ws[WS_MAP  + i]          = f2b(p.map_w[i]);
        else if (i < 49152) p.ws[WS_TMLP + (i - 32768)] = f2b(p.tmlp[i - 32768]);
        else if (i < 98304) p.ws[WS_MLP  + (i - 49152)] = f2b(p.mlp[i - 49152]);
    }
}

// ---------- featurize, intra-wave split: lane (h = lane>>5, pt = lane&31) ----------
// Each point is handled by TWO lanes: h=0 -> grid levels 0,1 (ch 0..31) + FFM ch 64..95;
// h=1 -> grid levels 2,3 (ch 32..63) + FFM ch 96..127. Branchless in h (level index
// is a per-lane runtime value -> cndmask selects, no exec-mask divergence, so the
// two halves' gathers pipeline in parallel within the wave).
template<int USE_WS, int HASB>
__device__ __forceinline__ void featurize32(const u16* __restrict__ gT, GridPtrs gp, int h,
                                            float x, float y, float z,
                                            const float* __restrict__ pe_w,
                                            const float* __restrict__ pe_b,
                                            u16* __restrict__ actw, int row)
{
#pragma unroll
    for (int lv2 = 0; lv2 < 2; ++lv2) {
        const int l = h * 2 + lv2;                 // lane-varying level index
        const int S   = (l == 0) ? 16 : (l == 1) ? 32 : (l == 2) ? 64 : 96;
        const int OFF = (l == 0) ? 0  : (l == 1) ? 65536 : (l == 2) ? 589824 : 4784128;
        const float fS = (float)(S - 1);
        float px = fminf(fmaxf((x + 1.f) * 0.5f * fS, 0.f), fS);
        float py = fminf(fmaxf((y + 1.f) * 0.5f * fS, 0.f), fS);
        float pz = fminf(fmaxf((z + 1.f) * 0.5f * fS, 0.f), fS);
        int ix0 = (int)px, iy0 = (int)py, iz0 = (int)pz;
        float wx = px - (float)ix0, wy = py - (float)iy0, wz = pz - (float)iz0;
        int ix1 = min(ix0 + 1, S - 1), iy1 = min(iy0 + 1, S - 1), iz1 = min(iz0 + 1, S - 1);
        // strength-reduced corner addressing: base + {0,dx} + {0,dy} + {0,dz}
        int dx = ix1 - ix0;
        int dy = (iy1 - iy0) * S;
        int dz = (iz1 - iz0) * S * S;
        int i000 = (iz0 * S + iy0) * S + ix0;

        float f[16];
#pragma unroll
        for (int c = 0; c < 16; ++c) f[c] = 0.f;

#pragma unroll
        for (int cz = 0; cz < 2; ++cz) {
            float wgtz = cz ? wz : (1.f - wz);
            int iz = cz ? dz : 0;
#pragma unroll
            for (int cy = 0; cy < 2; ++cy) {
                float wgty = wgtz * (cy ? wy : (1.f - wy));
                int izy = iz + (cy ? dy : 0);
#pragma unroll
                for (int cx = 0; cx < 2; ++cx) {
                    float wgt = wgty * (cx ? wx : (1.f - wx));
                    int idx = i000 + izy + (cx ? dx : 0);
                    if (USE_WS) {
                        const uint4* p = (const uint4*)(gT + OFF + (size_t)idx * 16);
                        uint4 a = p[0], b = p[1];
                        f[0]  += wgt * b2f((u16)(a.x & 0xffff));  f[1]  += wgt * b2f((u16)(a.x >> 16));
                        f[2]  += wgt * b2f((u16)(a.y & 0xffff));  f[3]  += wgt * b2f((u16)(a.y >> 16));
                        f[4]  += wgt * b2f((u16)(a.z & 0xffff));  f[5]  += wgt * b2f((u16)(a.z >> 16));
                        f[6]  += wgt * b2f((u16)(a.w & 0xffff));  f[7]  += wgt * b2f((u16)(a.w >> 16));
                        f[8]  += wgt * b2f((u16)(b.x & 0xffff));  f[9]  += wgt * b2f((u16)(b.x >> 16));
                        f[10] += wgt * b2f((u16)(b.y & 0xffff));  f[11] += wgt * b2f((u16)(b.y >> 16));
                        f[12] += wgt * b2f((u16)(b.z & 0xffff));  f[13] += wgt * b2f((u16)(b.z >> 16));
                        f[14] += wgt * b2f((u16)(b.w & 0xffff));  f[15] += wgt * b2f((u16)(b.w >> 16));
                    } else {
                        const float* gf = (l == 0) ? gp.g[0] : (l == 1) ? gp.g[1]
                                        : (l == 2) ? gp.g[2] : gp.g[3];
                        const int S3 = S * S * S;
#pragma unroll
                        for (int c = 0; c < 16; ++c)
                            f[c] += wgt * gf[(size_t)c * S3 + idx];
                    }
                }
            }
        }
#pragma unroll
        for (int c = 0; c < 16; c += 4)
            store4(actw, row, l * 16 + c,
                   fsilu(f[c]), fsilu(f[c + 1]), fsilu(f[c + 2]), fsilu(f[c + 3]));
    }
    // FFM: sin(coords @ pe_w^T (+ b)) -> channels 64 + h*32 .. 64 + h*32 + 31
    const int f0 = h * 32;
#pragma unroll 4
    for (int fc = 0; fc < 32; fc += 4) {
        float s[4];
#pragma unroll
        for (int j = 0; j < 4; ++j) {
            int ch = f0 + fc + j;
            float a = x * pe_w[ch * 3 + 0] + y * pe_w[ch * 3 + 1] + z * pe_w[ch * 3 + 2];
            if (HASB) a += pe_b[ch];
            s[j] = fsin(a);
        }
        store4(actw, row, 64 + f0 + fc, s[0], s[1], s[2], s[3]);
    }
}

// ---------- per-wave 128x32 layer: D(out_ch, pt) = W(128x128) x act^T, 2 nt tiles ----------
__device__ __forceinline__ void loadB(const u16* actw, bf16x8 B[2][4], int l16, int quad) {
#pragma unroll
    for (int nt = 0; nt < 2; ++nt)
#pragma unroll
        for (int kt = 0; kt < 4; ++kt)
            B[nt][kt] = *(const bf16x8*)(actw + aidx(nt * 16 + l16, kt * 32 + quad * 8));
    ldsfence();   // pin loads BEFORE the in-place epilogue stores that follow
}

template<int USE_WS>
__device__ __forceinline__ bf16x8 loadA(const u16* WT, const float* Wf, int row, int chunk) {
    if (USE_WS) {
        return ((const bf16x8*)WT)[row * 16 + chunk];
    } else {
        const float4* p = (const float4*)(Wf + row * 128 + chunk * 8);
        float4 f0 = p[0], f1 = p[1];
        u32 w0 = (u32)f2b(f0.x) | ((u32)f2b(f0.y) << 16);
        u32 w1 = (u32)f2b(f0.z) | ((u32)f2b(f0.w) << 16);
        u32 w2 = (u32)f2b(f1.x) | ((u32)f2b(f1.y) << 16);
        u32 w3 = (u32)f2b(f1.z) | ((u32)f2b(f1.w) << 16);
        uint4 packed = make_uint4(w0, w1, w2, w3);
        bf16x8 r; __builtin_memcpy(&r, &packed, 16); return r;
    }
}

// mt unroll 2: caps the A-load pipeline at ~8 in-flight b128 loads (32 VGPRs)
// — full unroll's 128-reg pipeline is what pushed R0 to 224 VGPR.
// NOTE (R4 lesson, rule #20): with unroll 2, mt is RUNTIME inside the loop —
// any per-thread register array indexed by mt goes to scratch. All epilogue
// state must therefore live in LDS (position-addressed), never in reg arrays.
template<int USE_WS, typename Epi>
__device__ __forceinline__ void gemm128(const u16* __restrict__ WT, const float* __restrict__ Wf,
                                        const bf16x8 B[2][4],
                                        int l16, int quad, Epi&& epi)
{
#pragma unroll 2
    for (int mt = 0; mt < 8; ++mt) {
        f32x4 acc[2];
#pragma unroll
        for (int nt = 0; nt < 2; ++nt) acc[nt] = (f32x4){0.f, 0.f, 0.f, 0.f};
#pragma unroll
        for (int kt = 0; kt < 4; ++kt) {
            // A frag: W[mt*16 + (lane&15)][kt*32 + quad*8 .. +7]
            bf16x8 a = loadA<USE_WS>(WT, Wf, mt * 16 + l16, kt * 4 + quad);
#pragma unroll
            for (int nt = 0; nt < 2; ++nt)
                acc[nt] = __builtin_amdgcn_mfma_f32_16x16x32_bf16(a, B[nt][kt], acc[nt], 0, 0, 0);
        }
#pragma unroll
        for (int nt = 0; nt < 2; ++nt) epi(mt, nt, acc[nt]);
    }
}

// ---------- fused main kernel: one block = one wave = 32 points ----------
// R0's single-wave structure (zero barrier cost, homogeneous lanes) with the
// per-wave tile halved (32 pts). tfp lives in a second 8 KiB LDS tile — R4
// kept it in tfpPk[32] regs, but unroll-2's runtime mt made the array
// runtime-indexed -> scratch (137 MB writes + 134 MB reads, the WRITE_SIZE
// smoking gun). LDS total 16 KiB/block -> 10 blocks/CU cap (above measured
// ~7 resident). VGPR ~96 -> 5 waves/SIMD cap.
template<int USE_WS>
__global__ void __launch_bounds__(64)
dtn_main(const float* __restrict__ nc, const float* __restrict__ tauP,
         const float* __restrict__ phys, const u16* __restrict__ wsT,
         GridPtrs vgp, GridPtrs tgp,
         const float* __restrict__ vec_pe_w, const float* __restrict__ tau_pe_w,
         const float* __restrict__ tau_pe_b, const float* __restrict__ vscale,
         const float* __restrict__ map_w, const float* __restrict__ tau_mlp_w,
         const float* __restrict__ mlp_w, const float* __restrict__ tau_pars,
         const float* __restrict__ last_w, float* __restrict__ outP)
{
    __shared__ __align__(16) u16 actw[32 * 128];   // 8 KiB, one 32x128 bf16 tile
    __shared__ __align__(16) u16 tfpw[32 * 128];   // 8 KiB, tfp stash (LDS, not regs: rule #20)
    const int lane = threadIdx.x;
    const int h    = lane >> 5;           // featurize half (levels 2h,2h+1 + 32 FFM)
    const int pt   = lane & 31;           // featurize row (point-in-block)
    const int quad = lane >> 4, l16 = lane & 15;

    const int pBase = blockIdx.x * 32;
    const int fzPt  = pBase + pt;         // point this lane featurizes (2 lanes/pt)

    float cx = nc[fzPt * 3 + 0];
    float cy = nc[fzPt * 3 + 1];
    float cz = nc[fzPt * 3 + 2];

    float tauv[2];
#pragma unroll
    for (int nt = 0; nt < 2; ++nt) tauv[nt] = tauP[pBase + nt * 16 + l16];

    const u16* wsVec = wsT;
    const u16* wsTau = wsT + WS_TAU;
    const u16* wMap  = wsT + WS_MAP;
    const u16* wTmlp = wsT + WS_TMLP;
    const u16* wMlp  = wsT + WS_MLP;

    // ---- tau featurize ----
    featurize32<USE_WS, 1>(wsTau, tgp, h, cx, cy, cz, tau_pe_w, tau_pe_b, actw, pt);
    __syncthreads();

    // ---- tfp = tau_features @ tau_mlp_w^T -> LDS stash (bf16, true (pt,ch) positions) ----
    bf16x8 B[2][4];
    loadB(actw, B, l16, quad);
    gemm128<USE_WS>(wTmlp, tau_mlp_w, B, l16, quad, [&](int mt, int nt, f32x4 acc) {
        int cb = mt * 16 + quad * 4, prow = nt * 16 + l16;
        store4(tfpw, prow, cb, acc[0], acc[1], acc[2], acc[3]);
    });
    __syncthreads();

    // ---- vec featurize (overwrite act) ----
    featurize32<USE_WS, 0>(wsVec, vgp, h, cx, cy, cz, vec_pe_w, (const float*)nullptr, actw, pt);
    __syncthreads();

    // ---- vec_map layer 0: act = silu(act @ W0^T) ----
    loadB(actw, B, l16, quad);
    gemm128<USE_WS>(wMap, map_w, B, l16, quad, [&](int mt, int nt, f32x4 acc) {
        int cb = mt * 16 + quad * 4, prow = nt * 16 + l16;
        store4(actw, prow, cb, fsilu(acc[0]), fsilu(acc[1]), fsilu(acc[2]), fsilu(acc[3]));
    });
    __syncthreads();

    // ---- vec_map layer 1 fused with out-init: act = tanh(tau * vscale * silu(.)) ----
    loadB(actw, B, l16, quad);
    gemm128<USE_WS>(wMap + 128 * 128, map_w + 128 * 128, B, l16, quad, [&](int mt, int nt, f32x4 acc) {
        int cb = mt * 16 + quad * 4, prow = nt * 16 + l16;
        float t = tauv[nt];
        float4 vs = *(const float4*)(vscale + cb);
        store4(actw, prow, cb,
               ftanh(t * vs.x * fsilu(acc[0])), ftanh(t * vs.y * fsilu(acc[1])),
               ftanh(t * vs.z * fsilu(acc[2])), ftanh(t * vs.w * fsilu(acc[3])));
    });
    __syncthreads();

    // ---- 3 residual layers: out += tanh(tau*tp) * silu(out @ Wv^T [* tfp @ idx0]) ----
#pragma unroll
    for (int idx = 0; idx < 3; ++idx) {
        loadB(actw, B, l16, quad);
        gemm128<USE_WS>(wMlp + idx * 128 * 128, mlp_w + idx * 128 * 128, B, l16, quad,
                        [&](int mt, int nt, f32x4 acc) {
            int cb = mt * 16 + quad * 4, prow = nt * 16 + l16;
            float t = tauv[nt];
            float4 tp = *(const float4*)(tau_pars + idx * 128 + cb);
            uint2 old = *(const uint2*)(actw + aidx(prow, cb));
            float h0 = acc[0], h1 = acc[1], h2 = acc[2], h3 = acc[3];
            if (idx == 0) {
                uint2 tf = *(const uint2*)(tfpw + aidx(prow, cb));
                h0 *= b2f((u16)(tf.x & 0xffff));
                h1 *= b2f((u16)(tf.x >> 16));
                h2 *= b2f((u16)(tf.y & 0xffff));
                h3 *= b2f((u16)(tf.y >> 16));
            }
            float n0 = b2f((u16)(old.x & 0xffff)) + ftanh(t * tp.x) * fsilu(h0);
            float n1 = b2f((u16)(old.x >> 16))    + ftanh(t * tp.y) * fsilu(h1);
            float n2 = b2f((u16)(old.y & 0xffff)) + ftanh(t * tp.z) * fsilu(h2);
            float n3 = b2f((u16)(old.y >> 16))    + ftanh(t * tp.w) * fsilu(h3);
            store4(actw, prow, cb, n0, n1, n2, n3);
        });
        __syncthreads();
    }

    // ---- head: out = physical + act_row @ last_w^T  (3x128); 2 lanes per point,
    //      lane h covers k = h*64 .. h*64+63, then one shfl_xor(32) reduce ----
    float a0 = 0.f, a1 = 0.f, a2 = 0.f;
#pragma unroll
    for (int c8 = 0; c8 < 8; ++c8) {
        int kb = h * 64 + c8 * 8;
        bf16x8 v = *(const bf16x8*)(actw + aidx(pt, kb));
        const u16* vp = (const u16*)&v;
#pragma unroll
        for (int j = 0; j < 8; ++j) {
            float av = b2f(vp[j]);
            int k = kb + j;
            a0 += av * last_w[0 * 128 + k];
            a1 += av * last_w[1 * 128 + k];
            a2 += av * last_w[2 * 128 + k];
        }
    }
    a0 += __shfl_xor(a0, 32);
    a1 += __shfl_xor(a1, 32);
    a2 += __shfl_xor(a2, 32);
    if (h == 0) {
        outP[fzPt * 3 + 0] = phys[fzPt * 3 + 0] + a0;
        outP[fzPt * 3 + 1] = phys[fzPt * 3 + 1] + a1;
        outP[fzPt * 3 + 2] = phys[fzPt * 3 + 2] + a2;
    }
}

// ---------- launch ----------
extern "C" void kernel_launch(void* const* d_in, const int* in_sizes, int n_in,
                              void* d_out, int out_size, void* d_ws, size_t ws_size,
                              hipStream_t stream)
{
    // Supports both documented dict order (grids interleaved vec_g0,tau_g0,...)
    // and reference-signature order (vec_g0..3 then tau_g0..3). Slots 0-2 and
    // 11-19 are identical in both. Detect via in_sizes[4]: 65536 -> interleaved.
    const float* phys     = (const float*)d_in[0];
    const float* nc       = (const float*)d_in[1];
    const float* tau      = (const float*)d_in[2];
    GridPtrs vgp, tgp;
    bool interleaved = (in_sizes[4] == 65536);
    for (int l = 0; l < 4; ++l) {
        if (interleaved) {
            vgp.g[l] = (const float*)d_in[3 + 2 * l];
            tgp.g[l] = (const float*)d_in[4 + 2 * l];
        } else {
            vgp.g[l] = (const float*)d_in[3 + l];
            tgp.g[l] = (const float*)d_in[7 + l];
        }
    }
    const float* vec_pe_w = (const float*)d_in[11];
    const float* tau_pe_w = (const float*)d_in[12];
    const float* tau_pe_b = (const float*)d_in[13];
    const float* vscale   = (const float*)d_in[14];
    const float* map_w    = (const float*)d_in[15];
    const float* tau_mlp  = (const float*)d_in[16];
    const float* mlp_w    = (const float*)d_in[17];
    const float* tau_pars = (const float*)d_in[18];
    const float* last_w   = (const float*)d_in[19];
    u16* wsT = (u16*)d_ws;

    bool useWs = (ws_size >= WS_TOTAL_BYTES);
    if (useWs) {
        PrepArgs pa;
        for (int l = 0; l < 4; ++l) { pa.vg[l] = vgp.g[l]; pa.tg[l] = tgp.g[l]; }
        pa.map_w = map_w; pa.tmlp = tau_mlp; pa.mlp = mlp_w; pa.ws = wsT;
        dtn_prep<<<PREP_VOXB + 384, 256, 0, stream>>>(pa);
        dtn_main<1><<<N_PTS / 32, 64, 0, stream>>>(nc, tau, phys, wsT, vgp, tgp,
                                                   vec_pe_w, tau_pe_w, tau_pe_b, vscale,
                                                   map_w, tau_mlp, mlp_w, tau_pars, last_w,
                                                   (float*)d_out);
    } else {
        dtn_main<0><<<N_PTS / 32, 64, 0, stream>>>(nc, tau, phys, wsT, vgp, tgp,
                                                   vec_pe_w, tau_pe_w, tau_pe_b, vscale,
                                                   map_w, tau_mlp, mlp_w, tau_pars, last_w,
                                                   (float*)d_out);
    }
}